// Round 1
// baseline (237.927 us; speedup 1.0000x reference)
//
#include <hip/hip_runtime.h>

#define NV    100000
#define NE    20000
#define NNZT  1000000
#define DIM   64

// edge buckets: 16 edges each
#define EBITS 4
#define ELOC  16
#define EBK   (NE / ELOC)                 // 1250
#define CAP_E 1024
#define ESH   17
#define EMASK 0x1FFFF

// vertex buckets: 64 vertices each
#define VBITS 6
#define VLOC  64
#define VBK   ((NV + VLOC - 1) / VLOC)    // 1563
#define CAP_V 896
#define VSH   15
#define VMASK 0x7FFF

#define CHUNK 4096
#define NBIN  ((NNZT + CHUNK - 1) / CHUNK)   // 245

typedef __attribute__((ext_vector_type(8))) short bf16x8;
typedef __attribute__((ext_vector_type(4))) float f32x4;
typedef __attribute__((ext_vector_type(4))) unsigned short u16x4;

__device__ __forceinline__ float bf2f(unsigned short u) {
    return __uint_as_float(((unsigned)u) << 16);
}
__device__ __forceinline__ unsigned short f2bf(float f) {
    unsigned u = __float_as_uint(f);
    u += 0x7FFF + ((u >> 16) & 1);           // round-nearest-even
    return (unsigned short)(u >> 16);
}

// ---------------- one-pass binning into fixed-capacity bucket slabs (proven) ----------------
__global__ __launch_bounds__(256) void bin_kernel(
    const int* __restrict__ vertex, const int* __restrict__ edges,
    int* __restrict__ ecur, int* __restrict__ vcur,
    unsigned int* __restrict__ erecs, unsigned int* __restrict__ vrecs) {
    __shared__ int hE[EBK], hV[VBK];
    __shared__ int cE[EBK], cV[VBK];
    int tid = threadIdx.x;
    for (int t = tid; t < EBK; t += 256) hE[t] = 0;
    for (int t = tid; t < VBK; t += 256) hV[t] = 0;
    __syncthreads();
    int base4 = blockIdx.x * (CHUNK / 4);
    #pragma unroll
    for (int k = 0; k < CHUNK / 4 / 256; k++) {
        int i = base4 + k * 256 + tid;
        if (i < NNZT / 4) {
            int4 e = ((const int4*)edges)[i];
            int4 v = ((const int4*)vertex)[i];
            atomicAdd(&hE[e.x >> EBITS], 1); atomicAdd(&hE[e.y >> EBITS], 1);
            atomicAdd(&hE[e.z >> EBITS], 1); atomicAdd(&hE[e.w >> EBITS], 1);
            atomicAdd(&hV[v.x >> VBITS], 1); atomicAdd(&hV[v.y >> VBITS], 1);
            atomicAdd(&hV[v.z >> VBITS], 1); atomicAdd(&hV[v.w >> VBITS], 1);
        }
    }
    __syncthreads();
    for (int t = tid; t < EBK; t += 256) { int h = hE[t]; cE[t] = h ? atomicAdd(&ecur[t], h) : 0; }
    for (int t = tid; t < VBK; t += 256) { int h = hV[t]; cV[t] = h ? atomicAdd(&vcur[t], h) : 0; }
    __syncthreads();
    #pragma unroll
    for (int k = 0; k < CHUNK / 4 / 256; k++) {
        int i = base4 + k * 256 + tid;
        if (i < NNZT / 4) {
            int4 e = ((const int4*)edges)[i];
            int4 v = ((const int4*)vertex)[i];
            int be, bv, p;
            be = e.x >> EBITS; p = atomicAdd(&cE[be], 1); if (p < CAP_E) erecs[be * CAP_E + p] = ((unsigned)(e.x & 15) << ESH) | (unsigned)v.x;
            be = e.y >> EBITS; p = atomicAdd(&cE[be], 1); if (p < CAP_E) erecs[be * CAP_E + p] = ((unsigned)(e.y & 15) << ESH) | (unsigned)v.y;
            be = e.z >> EBITS; p = atomicAdd(&cE[be], 1); if (p < CAP_E) erecs[be * CAP_E + p] = ((unsigned)(e.z & 15) << ESH) | (unsigned)v.z;
            be = e.w >> EBITS; p = atomicAdd(&cE[be], 1); if (p < CAP_E) erecs[be * CAP_E + p] = ((unsigned)(e.w & 15) << ESH) | (unsigned)v.w;
            bv = v.x >> VBITS; p = atomicAdd(&cV[bv], 1); if (p < CAP_V) vrecs[bv * CAP_V + p] = ((unsigned)(v.x & 63) << VSH) | (unsigned)e.x;
            bv = v.y >> VBITS; p = atomicAdd(&cV[bv], 1); if (p < CAP_V) vrecs[bv * CAP_V + p] = ((unsigned)(v.y & 63) << VSH) | (unsigned)e.y;
            bv = v.z >> VBITS; p = atomicAdd(&cV[bv], 1); if (p < CAP_V) vrecs[bv * CAP_V + p] = ((unsigned)(v.z & 63) << VSH) | (unsigned)e.z;
            bv = v.w >> VBITS; p = atomicAdd(&cV[bv], 1); if (p < CAP_V) vrecs[bv * CAP_V + p] = ((unsigned)(v.w & 63) << VSH) | (unsigned)e.w;
        }
    }
}

// ---------------- weight convert+transpose: W1T[n][k]=bf16(W1[k][n]) ----------------
__global__ __launch_bounds__(256) void conv_w(
    const float* __restrict__ W1, const float* __restrict__ W2,
    unsigned short* __restrict__ W1T, unsigned short* __restrict__ W2T) {
    int tid = threadIdx.x;
    for (int t = tid; t < DIM * DIM; t += 256) {
        int k = t >> 6, n = t & 63;
        W1T[n * DIM + k] = f2bf(W1[k * DIM + n]);
        W2T[n * DIM + k] = f2bf(W2[k * DIM + n]);
    }
}

// ---------------- edge aggregation: counting sort + 4-records-per-load gather ----------------
// rows split across 16 lanes (f32x4 each); 4 lane-groups handle 4 records per instruction.
__global__ __launch_bounds__(256, 4) void agg_edges_srt(
    const float* __restrict__ X,
    const int* __restrict__ ebc, const unsigned int* __restrict__ erecs,
    unsigned short* __restrict__ Xeb) {
    __shared__ int rbuf[CAP_E];
    __shared__ int sbuf[CAP_E];
    __shared__ int boff[ELOC + 1];
    __shared__ int bcur[ELOC];
    int tid = threadIdx.x;
    int b = blockIdx.x;
    int cnt = ebc[b]; if (cnt > CAP_E) cnt = CAP_E;
    const unsigned int* src = erecs + (size_t)b * CAP_E;
    for (int t = tid; t < cnt; t += 256) rbuf[t] = (int)src[t];
    if (tid < ELOC) bcur[tid] = 0;
    __syncthreads();
    for (int t = tid; t < cnt; t += 256) atomicAdd(&bcur[((unsigned)rbuf[t]) >> ESH], 1);
    __syncthreads();
    if (tid < 64) {  // wave 0: parallel exclusive scan of 16 entries
        int lane = tid;
        int c = (lane < ELOC) ? bcur[lane] : 0;
        int s = c;
        #pragma unroll
        for (int d = 1; d < ELOC; d <<= 1) {
            int t2 = __shfl_up(s, d);
            if (lane >= d) s += t2;
        }
        if (lane < ELOC) { boff[lane] = s - c; bcur[lane] = s - c; }
        if (lane == ELOC - 1) boff[ELOC] = s;
    }
    __syncthreads();
    for (int t = tid; t < cnt; t += 256) {
        unsigned r = (unsigned)rbuf[t];
        int p = atomicAdd(&bcur[r >> ESH], 1);
        sbuf[p] = (int)(r & EMASK);
    }
    __syncthreads();

    int wave = tid >> 6, lane = tid & 63;
    int g = lane >> 4, m = lane & 15;
    #pragma unroll
    for (int q = 0; q < 4; q++) {
        int le = wave * 4 + q;
        int beg = boff[le], end = boff[le + 1];
        f32x4 acc = {0.f, 0.f, 0.f, 0.f};
        f32x4 acc2 = {0.f, 0.f, 0.f, 0.f};
        int jj = beg;
        for (; jj + 8 <= end; jj += 8) {        // 8 records / iter, 2 loads in flight
            int v0 = sbuf[jj + g];
            int v1 = sbuf[jj + 4 + g];
            f32x4 a0 = *(const f32x4*)(X + ((size_t)v0 << 6) + (m << 2));
            f32x4 a1 = *(const f32x4*)(X + ((size_t)v1 << 6) + (m << 2));
            acc += a0; acc2 += a1;
        }
        for (; jj < end; jj += 4) {
            int idx = jj + g;
            if (idx < end) {
                int v0 = sbuf[idx];
                acc += *(const f32x4*)(X + ((size_t)v0 << 6) + (m << 2));
            }
        }
        acc += acc2;
        #pragma unroll
        for (int k = 0; k < 4; k++) {           // fold 4 lane-groups
            acc[k] += __shfl_xor(acc[k], 16);
            acc[k] += __shfl_xor(acc[k], 32);
        }
        if (g == 0) {
            u16x4 ub;
            #pragma unroll
            for (int k = 0; k < 4; k++) ub[k] = f2bf(acc[k]);
            *(u16x4*)(Xeb + (((size_t)(b * ELOC + le)) << 6) + (m << 2)) = ub;
        }
    }
}

// ---------------- fused vertex aggregation + MLP (MFMA) ----------------
// gather: 4 records per ushort4 load; xi kept as bf16 in LDS (stride-72 rows);
// each wave then runs the 2-layer MFMA MLP on its own 16 rows (all LDS wave-local,
// no cross-wave barrier needed) and writes the final blended output once.
__global__ __launch_bounds__(256, 4) void agg_verts_mlp(
    const unsigned short* __restrict__ Xeb, const float* __restrict__ X0,
    const int* __restrict__ vbc, const unsigned int* __restrict__ vrecs,
    const unsigned short* __restrict__ W1T, const unsigned short* __restrict__ W2T,
    const float* __restrict__ b1, const float* __restrict__ b2,
    float* __restrict__ out) {
    __shared__ int rbuf[CAP_V];
    __shared__ int sbuf[CAP_V];
    __shared__ int boff[VLOC + 1];
    __shared__ int bcur[VLOC];
    __shared__ __align__(16) unsigned short xib[VLOC * 72];   // xi bf16, row stride 72
    __shared__ __align__(16) unsigned short ht[4][16 * 72];   // gemm1->gemm2 relayout
    int tid = threadIdx.x;
    int b = blockIdx.x;
    int cnt = vbc[b]; if (cnt > CAP_V) cnt = CAP_V;
    const unsigned int* src = vrecs + (size_t)b * CAP_V;
    for (int t = tid; t < cnt; t += 256) rbuf[t] = (int)src[t];
    if (tid < VLOC) bcur[tid] = 0;
    __syncthreads();
    for (int t = tid; t < cnt; t += 256) atomicAdd(&bcur[((unsigned)rbuf[t]) >> VSH], 1);
    __syncthreads();
    if (tid < 64) {  // wave 0: parallel exclusive scan of 64 entries
        int lane = tid;
        int c = bcur[lane];
        int s = c;
        #pragma unroll
        for (int d = 1; d < 64; d <<= 1) {
            int t2 = __shfl_up(s, d);
            if (lane >= d) s += t2;
        }
        boff[lane] = s - c;
        bcur[lane] = s - c;
        if (lane == 63) boff[VLOC] = s;
    }
    __syncthreads();
    for (int t = tid; t < cnt; t += 256) {
        unsigned r = (unsigned)rbuf[t];
        int p = atomicAdd(&bcur[r >> VSH], 1);
        sbuf[p] = (int)(r & VMASK);
    }
    __syncthreads();

    int wave = tid >> 6, lane = tid & 63;
    int g = lane >> 4, m = lane & 15;
    int row0 = b << VBITS;

    // ---- gather: each wave owns 16 vertices; 4 records per load instruction ----
    for (int q = 0; q < 16; q++) {
        int lv = wave * 16 + q;
        int row = row0 + lv;
        if (row >= NV) continue;
        int beg = boff[lv], end = boff[lv + 1];
        f32x4 acc = {0.f, 0.f, 0.f, 0.f};
        f32x4 acc2 = {0.f, 0.f, 0.f, 0.f};
        int jj = beg;
        for (; jj + 8 <= end; jj += 8) {
            int e0 = sbuf[jj + g];
            int e1 = sbuf[jj + 4 + g];
            u16x4 u0 = *(const u16x4*)(Xeb + ((size_t)e0 << 6) + (m << 2));
            u16x4 u1 = *(const u16x4*)(Xeb + ((size_t)e1 << 6) + (m << 2));
            #pragma unroll
            for (int k = 0; k < 4; k++) { acc[k] += bf2f(u0[k]); acc2[k] += bf2f(u1[k]); }
        }
        for (; jj < end; jj += 4) {
            int idx = jj + g;
            if (idx < end) {
                int e0 = sbuf[idx];
                u16x4 u0 = *(const u16x4*)(Xeb + ((size_t)e0 << 6) + (m << 2));
                #pragma unroll
                for (int k = 0; k < 4; k++) acc[k] += bf2f(u0[k]);
            }
        }
        acc += acc2;
        #pragma unroll
        for (int k = 0; k < 4; k++) {
            acc[k] += __shfl_xor(acc[k], 16);
            acc[k] += __shfl_xor(acc[k], 32);
        }
        if (g == 0) {
            f32x4 x0v = *(const f32x4*)(X0 + ((size_t)row << 6) + (m << 2));
            u16x4 ub;
            #pragma unroll
            for (int k = 0; k < 4; k++) ub[k] = f2bf(0.5f * acc[k] + 0.5f * x0v[k]);
            *(u16x4*)(xib + lv * 72 + (m << 2)) = ub;
        }
    }

    // ---- MLP on this wave's own 16 rows (wave-local LDS; fence, no barrier) ----
    asm volatile("s_waitcnt lgkmcnt(0)" ::: "memory");
    int quad = g;
    const unsigned short* xr = xib + (wave * 16 + m) * 72;
    bf16x8 a0 = *(const bf16x8*)(xr + quad * 8);
    bf16x8 a1 = *(const bf16x8*)(xr + 32 + quad * 8);

    // gemm1: h = relu(xi @ W1 + b1); B-frags straight from L2-hot W1T
    f32x4 h[4];
    #pragma unroll
    for (int nt = 0; nt < 4; nt++) {
        float bias = b1[nt * 16 + m];
        f32x4 c = {bias, bias, bias, bias};
        const unsigned short* wb = W1T + (nt * 16 + m) * DIM;
        bf16x8 w0 = *(const bf16x8*)(wb + quad * 8);
        bf16x8 w1 = *(const bf16x8*)(wb + 32 + quad * 8);
        c = __builtin_amdgcn_mfma_f32_16x16x32_bf16(a0, w0, c, 0, 0, 0);
        c = __builtin_amdgcn_mfma_f32_16x16x32_bf16(a1, w1, c, 0, 0, 0);
        h[nt] = c;
    }

    // C-layout -> A-layout via per-wave LDS (bf16)
    unsigned short* hw = ht[wave];
    #pragma unroll
    for (int nt = 0; nt < 4; nt++) {
        #pragma unroll
        for (int r = 0; r < 4; r++) {
            float v = fmaxf(h[nt][r], 0.f);
            hw[(quad * 4 + r) * 72 + nt * 16 + m] = f2bf(v);
        }
    }
    asm volatile("s_waitcnt lgkmcnt(0)" ::: "memory");
    bf16x8 g0 = *(const bf16x8*)(hw + m * 72 + quad * 8);
    bf16x8 g1 = *(const bf16x8*)(hw + m * 72 + 32 + quad * 8);

    // gemm2: mlp = h @ W2 + b2
    f32x4 o[4];
    #pragma unroll
    for (int nt = 0; nt < 4; nt++) {
        float bias = b2[nt * 16 + m];
        f32x4 c = {bias, bias, bias, bias};
        const unsigned short* wb = W2T + (nt * 16 + m) * DIM;
        bf16x8 w0 = *(const bf16x8*)(wb + quad * 8);
        bf16x8 w1 = *(const bf16x8*)(wb + 32 + quad * 8);
        c = __builtin_amdgcn_mfma_f32_16x16x32_bf16(g0, w0, c, 0, 0, 0);
        c = __builtin_amdgcn_mfma_f32_16x16x32_bf16(g1, w1, c, 0, 0, 0);
        o[nt] = c;
    }

    // epilogue: out = 0.5*xi + 0.5*mlp — single write per element
    #pragma unroll
    for (int nt = 0; nt < 4; nt++) {
        #pragma unroll
        for (int r = 0; r < 4; r++) {
            int lrow = wave * 16 + quad * 4 + r;
            int row = row0 + lrow;
            if (row < NV) {
                float xi = bf2f(xib[lrow * 72 + nt * 16 + m]);
                out[(size_t)row * DIM + nt * 16 + m] = 0.5f * xi + 0.5f * o[nt][r];
            }
        }
    }
}

extern "C" void kernel_launch(void* const* d_in, const int* in_sizes, int n_in,
                              void* d_out, int out_size, void* d_ws, size_t ws_size,
                              hipStream_t stream) {
    const float* X  = (const float*)d_in[0];
    const float* X0 = (const float*)d_in[1];
    const float* W1 = (const float*)d_in[2];
    const float* b1 = (const float*)d_in[3];
    const float* W2 = (const float*)d_in[4];
    const float* b2 = (const float*)d_in[5];
    const int* vertex = (const int*)d_in[6];
    const int* edges  = (const int*)d_in[7];
    float* out = (float*)d_out;

    // workspace layout (16-byte aligned sections)
    char* p = (char*)d_ws;
    int* ecur = (int*)p;                          p += (size_t)EBK * 4;
    int* vcur = (int*)p;                          p += (size_t)VBK * 4;
    p = (char*)(((uintptr_t)p + 15) & ~(uintptr_t)15);
    unsigned int* erecs = (unsigned int*)p;       p += (size_t)EBK * CAP_E * 4;
    unsigned int* vrecs = (unsigned int*)p;       p += (size_t)VBK * CAP_V * 4;
    unsigned short* Xeb = (unsigned short*)p;     p += (size_t)NE * DIM * 2;
    unsigned short* W1T = (unsigned short*)p;     p += (size_t)DIM * DIM * 2;
    unsigned short* W2T = (unsigned short*)p;     p += (size_t)DIM * DIM * 2;

    hipMemsetAsync(d_ws, 0, (size_t)(EBK + VBK) * sizeof(int), stream);

    dim3 blk(256);
    bin_kernel<<<NBIN, blk, 0, stream>>>(vertex, edges, ecur, vcur, erecs, vrecs);
    conv_w<<<1, blk, 0, stream>>>(W1, W2, W1T, W2T);
    agg_edges_srt<<<EBK, blk, 0, stream>>>(X, ecur, erecs, Xeb);
    agg_verts_mlp<<<VBK, blk, 0, stream>>>(Xeb, X0, vcur, vrecs, W1T, W2T, b1, b2, out);
}

// Round 2
// 231.543 us; speedup vs baseline: 1.0276x; 1.0276x over previous
//
#include <hip/hip_runtime.h>

#define NV    100000
#define NE    20000
#define NNZT  1000000
#define DIM   64

// edge buckets: 16 edges each
#define EBITS 4
#define ELOC  16
#define EBK   (NE / ELOC)                 // 1250
#define CAP_E 1024
#define ESH   17
#define EMASK 0x1FFFF

// vertex buckets: 64 vertices each
#define VBITS 6
#define VLOC  64
#define VBK   ((NV + VLOC - 1) / VLOC)    // 1563
#define CAP_V 896
#define VSH   15
#define VMASK 0x7FFF

#define CHUNK 4096
#define NBIN  ((NNZT + CHUNK - 1) / CHUNK)   // 245

typedef __attribute__((ext_vector_type(8))) short bf16x8;
typedef __attribute__((ext_vector_type(4))) float f32x4;

__device__ __forceinline__ float bf2f(unsigned short u) {
    return __uint_as_float(((unsigned)u) << 16);
}
__device__ __forceinline__ unsigned short f2bf(float f) {
    unsigned u = __float_as_uint(f);
    u += 0x7FFF + ((u >> 16) & 1);           // round-nearest-even
    return (unsigned short)(u >> 16);
}

// ---- gather batch macros: all loads issued before any adds (max loads in flight) ----
#define PAIR8(LD, ACCA, JA, ACCB, JB) { \
    int ia0=sbuf[(JA)], ia1=sbuf[(JA)+1], ia2=sbuf[(JA)+2], ia3=sbuf[(JA)+3]; \
    int ia4=sbuf[(JA)+4], ia5=sbuf[(JA)+5], ia6=sbuf[(JA)+6], ia7=sbuf[(JA)+7]; \
    int ib0=sbuf[(JB)], ib1=sbuf[(JB)+1], ib2=sbuf[(JB)+2], ib3=sbuf[(JB)+3]; \
    int ib4=sbuf[(JB)+4], ib5=sbuf[(JB)+5], ib6=sbuf[(JB)+6], ib7=sbuf[(JB)+7]; \
    float fa0=LD(ia0), fa1=LD(ia1), fa2=LD(ia2), fa3=LD(ia3); \
    float fa4=LD(ia4), fa5=LD(ia5), fa6=LD(ia6), fa7=LD(ia7); \
    float fb0=LD(ib0), fb1=LD(ib1), fb2=LD(ib2), fb3=LD(ib3); \
    float fb4=LD(ib4), fb5=LD(ib5), fb6=LD(ib6), fb7=LD(ib7); \
    ACCA += ((fa0+fa1)+(fa2+fa3))+((fa4+fa5)+(fa6+fa7)); \
    ACCB += ((fb0+fb1)+(fb2+fb3))+((fb4+fb5)+(fb6+fb7)); }

#define ONE8(LD, ACC, J) { \
    int i0=sbuf[(J)], i1=sbuf[(J)+1], i2=sbuf[(J)+2], i3=sbuf[(J)+3]; \
    int i4=sbuf[(J)+4], i5=sbuf[(J)+5], i6=sbuf[(J)+6], i7=sbuf[(J)+7]; \
    float f0=LD(i0), f1=LD(i1), f2=LD(i2), f3=LD(i3); \
    float f4=LD(i4), f5=LD(i5), f6=LD(i6), f7=LD(i7); \
    ACC += ((f0+f1)+(f2+f3))+((f4+f5)+(f6+f7)); }

#define ONE4(LD, ACC, J) { \
    int i0=sbuf[(J)], i1=sbuf[(J)+1], i2=sbuf[(J)+2], i3=sbuf[(J)+3]; \
    float f0=LD(i0), f1=LD(i1), f2=LD(i2), f3=LD(i3); \
    ACC += (f0+f1)+(f2+f3); }

// ---------------- one-pass binning into fixed-capacity bucket slabs (proven) ----------------
__global__ __launch_bounds__(256) void bin_kernel(
    const int* __restrict__ vertex, const int* __restrict__ edges,
    int* __restrict__ ecur, int* __restrict__ vcur,
    unsigned int* __restrict__ erecs, unsigned int* __restrict__ vrecs) {
    __shared__ int hE[EBK], hV[VBK];
    __shared__ int cE[EBK], cV[VBK];
    int tid = threadIdx.x;
    for (int t = tid; t < EBK; t += 256) hE[t] = 0;
    for (int t = tid; t < VBK; t += 256) hV[t] = 0;
    __syncthreads();
    int base4 = blockIdx.x * (CHUNK / 4);
    #pragma unroll
    for (int k = 0; k < CHUNK / 4 / 256; k++) {
        int i = base4 + k * 256 + tid;
        if (i < NNZT / 4) {
            int4 e = ((const int4*)edges)[i];
            int4 v = ((const int4*)vertex)[i];
            atomicAdd(&hE[e.x >> EBITS], 1); atomicAdd(&hE[e.y >> EBITS], 1);
            atomicAdd(&hE[e.z >> EBITS], 1); atomicAdd(&hE[e.w >> EBITS], 1);
            atomicAdd(&hV[v.x >> VBITS], 1); atomicAdd(&hV[v.y >> VBITS], 1);
            atomicAdd(&hV[v.z >> VBITS], 1); atomicAdd(&hV[v.w >> VBITS], 1);
        }
    }
    __syncthreads();
    for (int t = tid; t < EBK; t += 256) { int h = hE[t]; cE[t] = h ? atomicAdd(&ecur[t], h) : 0; }
    for (int t = tid; t < VBK; t += 256) { int h = hV[t]; cV[t] = h ? atomicAdd(&vcur[t], h) : 0; }
    __syncthreads();
    #pragma unroll
    for (int k = 0; k < CHUNK / 4 / 256; k++) {
        int i = base4 + k * 256 + tid;
        if (i < NNZT / 4) {
            int4 e = ((const int4*)edges)[i];
            int4 v = ((const int4*)vertex)[i];
            int be, bv, p;
            be = e.x >> EBITS; p = atomicAdd(&cE[be], 1); if (p < CAP_E) erecs[be * CAP_E + p] = ((unsigned)(e.x & 15) << ESH) | (unsigned)v.x;
            be = e.y >> EBITS; p = atomicAdd(&cE[be], 1); if (p < CAP_E) erecs[be * CAP_E + p] = ((unsigned)(e.y & 15) << ESH) | (unsigned)v.y;
            be = e.z >> EBITS; p = atomicAdd(&cE[be], 1); if (p < CAP_E) erecs[be * CAP_E + p] = ((unsigned)(e.z & 15) << ESH) | (unsigned)v.z;
            be = e.w >> EBITS; p = atomicAdd(&cE[be], 1); if (p < CAP_E) erecs[be * CAP_E + p] = ((unsigned)(e.w & 15) << ESH) | (unsigned)v.w;
            bv = v.x >> VBITS; p = atomicAdd(&cV[bv], 1); if (p < CAP_V) vrecs[bv * CAP_V + p] = ((unsigned)(v.x & 63) << VSH) | (unsigned)e.x;
            bv = v.y >> VBITS; p = atomicAdd(&cV[bv], 1); if (p < CAP_V) vrecs[bv * CAP_V + p] = ((unsigned)(v.y & 63) << VSH) | (unsigned)e.y;
            bv = v.z >> VBITS; p = atomicAdd(&cV[bv], 1); if (p < CAP_V) vrecs[bv * CAP_V + p] = ((unsigned)(v.z & 63) << VSH) | (unsigned)e.z;
            bv = v.w >> VBITS; p = atomicAdd(&cV[bv], 1); if (p < CAP_V) vrecs[bv * CAP_V + p] = ((unsigned)(v.w & 63) << VSH) | (unsigned)e.w;
        }
    }
}

// ---------------- weight convert+transpose: W1T[n][k]=bf16(W1[k][n]) ----------------
__global__ __launch_bounds__(256) void conv_w(
    const float* __restrict__ W1, const float* __restrict__ W2,
    unsigned short* __restrict__ W1T, unsigned short* __restrict__ W2T) {
    int tid = threadIdx.x;
    for (int t = tid; t < DIM * DIM; t += 256) {
        int k = t >> 6, n = t & 63;
        W1T[n * DIM + k] = f2bf(W1[k * DIM + n]);
        W2T[n * DIM + k] = f2bf(W2[k * DIM + n]);
    }
}

// ---------------- edge aggregation: counting sort + paired-segment gather ----------------
// 64 lanes per record (4B/lane); two segments per chain-pair -> up to 16 loads in flight.
__global__ __launch_bounds__(256, 4) void agg_edges_srt(
    const float* __restrict__ X,
    const int* __restrict__ ebc, const unsigned int* __restrict__ erecs,
    unsigned short* __restrict__ Xeb) {
    __shared__ int rbuf[CAP_E];
    __shared__ int sbuf[CAP_E];
    __shared__ int boff[ELOC + 1];
    __shared__ int bcur[ELOC];
    int tid = threadIdx.x;
    int b = blockIdx.x;
    int cnt = ebc[b]; if (cnt > CAP_E) cnt = CAP_E;
    const unsigned int* src = erecs + (size_t)b * CAP_E;
    for (int t = tid; t < cnt; t += 256) rbuf[t] = (int)src[t];
    if (tid < ELOC) bcur[tid] = 0;
    __syncthreads();
    for (int t = tid; t < cnt; t += 256) atomicAdd(&bcur[((unsigned)rbuf[t]) >> ESH], 1);
    __syncthreads();
    if (tid < 64) {  // wave 0: parallel exclusive scan of 16 entries
        int lane = tid;
        int c = (lane < ELOC) ? bcur[lane] : 0;
        int s = c;
        #pragma unroll
        for (int d = 1; d < ELOC; d <<= 1) {
            int t2 = __shfl_up(s, d);
            if (lane >= d) s += t2;
        }
        if (lane < ELOC) { boff[lane] = s - c; bcur[lane] = s - c; }
        if (lane == ELOC - 1) boff[ELOC] = s;
    }
    __syncthreads();
    for (int t = tid; t < cnt; t += 256) {
        unsigned r = (unsigned)rbuf[t];
        int p = atomicAdd(&bcur[r >> ESH], 1);
        sbuf[p] = (int)(r & EMASK);
    }
    __syncthreads();

    int wave = tid >> 6, lane = tid & 63;
    #define LD_X(vv) X[((size_t)(vv) << 6) + lane]
    for (int t = 0; t < 2; t++) {
        int leA = wave * 4 + 2 * t, leB = leA + 1;
        int jA = boff[leA], eA = boff[leA + 1];
        int jB = boff[leB], eB = boff[leB + 1];
        float accA = 0.f, accB = 0.f;
        while (jA + 8 <= eA && jB + 8 <= eB) { PAIR8(LD_X, accA, jA, accB, jB); jA += 8; jB += 8; }
        while (jA + 8 <= eA) { ONE8(LD_X, accA, jA); jA += 8; }
        while (jB + 8 <= eB) { ONE8(LD_X, accB, jB); jB += 8; }
        if (jA + 4 <= eA) { ONE4(LD_X, accA, jA); jA += 4; }
        if (jB + 4 <= eB) { ONE4(LD_X, accB, jB); jB += 4; }
        while (jA < eA || jB < eB) {               // merged tail, uniform branches
            float va = 0.f, vb = 0.f;
            if (jA < eA) va = LD_X(sbuf[jA]);
            if (jB < eB) vb = LD_X(sbuf[jB]);
            accA += va; accB += vb;
            jA += (jA < eA); jB += (jB < eB);
        }
        Xeb[(((size_t)(b * ELOC + leA)) << 6) + lane] = f2bf(accA);
        Xeb[(((size_t)(b * ELOC + leB)) << 6) + lane] = f2bf(accB);
    }
    #undef LD_X
}

// ---------------- fused vertex aggregation + MLP (MFMA) ----------------
// gather: 64 lanes/record, paired segments (16 loads in flight); xi bf16 in LDS;
// each wave runs the 2-layer MFMA MLP on its own 16 rows (wave-local LDS, no barrier).
__global__ __launch_bounds__(256, 4) void agg_verts_mlp(
    const unsigned short* __restrict__ Xeb, const float* __restrict__ X0,
    const int* __restrict__ vbc, const unsigned int* __restrict__ vrecs,
    const unsigned short* __restrict__ W1T, const unsigned short* __restrict__ W2T,
    const float* __restrict__ b1, const float* __restrict__ b2,
    float* __restrict__ out) {
    __shared__ int rbuf[CAP_V];
    __shared__ int sbuf[CAP_V];
    __shared__ int boff[VLOC + 1];
    __shared__ int bcur[VLOC];
    __shared__ __align__(16) unsigned short xib[VLOC * 72];   // xi bf16, row stride 72
    __shared__ __align__(16) unsigned short ht[4][16 * 72];   // gemm1->gemm2 relayout
    int tid = threadIdx.x;
    int b = blockIdx.x;
    int cnt = vbc[b]; if (cnt > CAP_V) cnt = CAP_V;
    const unsigned int* src = vrecs + (size_t)b * CAP_V;
    for (int t = tid; t < cnt; t += 256) rbuf[t] = (int)src[t];
    if (tid < VLOC) bcur[tid] = 0;
    __syncthreads();
    for (int t = tid; t < cnt; t += 256) atomicAdd(&bcur[((unsigned)rbuf[t]) >> VSH], 1);
    __syncthreads();
    if (tid < 64) {  // wave 0: parallel exclusive scan of 64 entries
        int lane = tid;
        int c = bcur[lane];
        int s = c;
        #pragma unroll
        for (int d = 1; d < 64; d <<= 1) {
            int t2 = __shfl_up(s, d);
            if (lane >= d) s += t2;
        }
        boff[lane] = s - c;
        bcur[lane] = s - c;
        if (lane == 63) boff[VLOC] = s;
    }
    __syncthreads();
    for (int t = tid; t < cnt; t += 256) {
        unsigned r = (unsigned)rbuf[t];
        int p = atomicAdd(&bcur[r >> VSH], 1);
        sbuf[p] = (int)(r & VMASK);
    }
    __syncthreads();

    int wave = tid >> 6, lane = tid & 63;
    int row0 = b << VBITS;

    #define LD_E(vv) bf2f(Xeb[((size_t)(vv) << 6) + lane])
    for (int t = 0; t < 8; t++) {
        int lvA = wave * 16 + 2 * t, lvB = lvA + 1;
        int jA = boff[lvA], eA = boff[lvA + 1];
        int jB = boff[lvB], eB = boff[lvB + 1];
        float accA = 0.f, accB = 0.f;
        while (jA + 8 <= eA && jB + 8 <= eB) { PAIR8(LD_E, accA, jA, accB, jB); jA += 8; jB += 8; }
        while (jA + 8 <= eA) { ONE8(LD_E, accA, jA); jA += 8; }
        while (jB + 8 <= eB) { ONE8(LD_E, accB, jB); jB += 8; }
        if (jA + 4 <= eA) { ONE4(LD_E, accA, jA); jA += 4; }
        if (jB + 4 <= eB) { ONE4(LD_E, accB, jB); jB += 4; }
        while (jA < eA || jB < eB) {               // merged tail, uniform branches
            float va = 0.f, vb = 0.f;
            if (jA < eA) va = LD_E(sbuf[jA]);
            if (jB < eB) vb = LD_E(sbuf[jB]);
            accA += va; accB += vb;
            jA += (jA < eA); jB += (jB < eB);
        }
        int rowA = row0 + lvA, rowB = row0 + lvB;
        if (rowA < NV) xib[lvA * 72 + lane] = f2bf(0.5f * accA + 0.5f * X0[((size_t)rowA << 6) + lane]);
        else           xib[lvA * 72 + lane] = 0;
        if (rowB < NV) xib[lvB * 72 + lane] = f2bf(0.5f * accB + 0.5f * X0[((size_t)rowB << 6) + lane]);
        else           xib[lvB * 72 + lane] = 0;
    }
    #undef LD_E

    // ---- MLP on this wave's own 16 rows (wave-local LDS; fence, no barrier) ----
    asm volatile("s_waitcnt lgkmcnt(0)" ::: "memory");
    __builtin_amdgcn_sched_barrier(0);
    int quad = lane >> 4, m = lane & 15;
    const unsigned short* xr = xib + (wave * 16 + m) * 72;
    bf16x8 a0 = *(const bf16x8*)(xr + quad * 8);
    bf16x8 a1 = *(const bf16x8*)(xr + 32 + quad * 8);

    // gemm1: h = relu(xi @ W1 + b1); B-frags straight from L2-hot W1T
    f32x4 h[4];
    #pragma unroll
    for (int nt = 0; nt < 4; nt++) {
        float bias = b1[nt * 16 + m];
        f32x4 c = {bias, bias, bias, bias};
        const unsigned short* wb = W1T + (nt * 16 + m) * DIM;
        bf16x8 w0 = *(const bf16x8*)(wb + quad * 8);
        bf16x8 w1 = *(const bf16x8*)(wb + 32 + quad * 8);
        c = __builtin_amdgcn_mfma_f32_16x16x32_bf16(a0, w0, c, 0, 0, 0);
        c = __builtin_amdgcn_mfma_f32_16x16x32_bf16(a1, w1, c, 0, 0, 0);
        h[nt] = c;
    }

    // C-layout -> A-layout via per-wave LDS (bf16)
    unsigned short* hw = ht[wave];
    #pragma unroll
    for (int nt = 0; nt < 4; nt++) {
        #pragma unroll
        for (int r = 0; r < 4; r++) {
            float v = fmaxf(h[nt][r], 0.f);
            hw[(quad * 4 + r) * 72 + nt * 16 + m] = f2bf(v);
        }
    }
    asm volatile("s_waitcnt lgkmcnt(0)" ::: "memory");
    __builtin_amdgcn_sched_barrier(0);
    bf16x8 g0 = *(const bf16x8*)(hw + m * 72 + quad * 8);
    bf16x8 g1 = *(const bf16x8*)(hw + m * 72 + 32 + quad * 8);

    // gemm2: mlp = h @ W2 + b2
    f32x4 o[4];
    #pragma unroll
    for (int nt = 0; nt < 4; nt++) {
        float bias = b2[nt * 16 + m];
        f32x4 c = {bias, bias, bias, bias};
        const unsigned short* wb = W2T + (nt * 16 + m) * DIM;
        bf16x8 w0 = *(const bf16x8*)(wb + quad * 8);
        bf16x8 w1 = *(const bf16x8*)(wb + 32 + quad * 8);
        c = __builtin_amdgcn_mfma_f32_16x16x32_bf16(g0, w0, c, 0, 0, 0);
        c = __builtin_amdgcn_mfma_f32_16x16x32_bf16(g1, w1, c, 0, 0, 0);
        o[nt] = c;
    }

    // epilogue: out = 0.5*xi + 0.5*mlp — single write per element
    #pragma unroll
    for (int nt = 0; nt < 4; nt++) {
        #pragma unroll
        for (int r = 0; r < 4; r++) {
            int lrow = wave * 16 + quad * 4 + r;
            int row = row0 + lrow;
            if (row < NV) {
                float xi = bf2f(xib[lrow * 72 + nt * 16 + m]);
                out[(size_t)row * DIM + nt * 16 + m] = 0.5f * xi + 0.5f * o[nt][r];
            }
        }
    }
}

extern "C" void kernel_launch(void* const* d_in, const int* in_sizes, int n_in,
                              void* d_out, int out_size, void* d_ws, size_t ws_size,
                              hipStream_t stream) {
    const float* X  = (const float*)d_in[0];
    const float* X0 = (const float*)d_in[1];
    const float* W1 = (const float*)d_in[2];
    const float* b1 = (const float*)d_in[3];
    const float* W2 = (const float*)d_in[4];
    const float* b2 = (const float*)d_in[5];
    const int* vertex = (const int*)d_in[6];
    const int* edges  = (const int*)d_in[7];
    float* out = (float*)d_out;

    // workspace layout (16-byte aligned sections)
    char* p = (char*)d_ws;
    int* ecur = (int*)p;                          p += (size_t)EBK * 4;
    int* vcur = (int*)p;                          p += (size_t)VBK * 4;
    p = (char*)(((uintptr_t)p + 15) & ~(uintptr_t)15);
    unsigned int* erecs = (unsigned int*)p;       p += (size_t)EBK * CAP_E * 4;
    unsigned int* vrecs = (unsigned int*)p;       p += (size_t)VBK * CAP_V * 4;
    unsigned short* Xeb = (unsigned short*)p;     p += (size_t)NE * DIM * 2;
    unsigned short* W1T = (unsigned short*)p;     p += (size_t)DIM * DIM * 2;
    unsigned short* W2T = (unsigned short*)p;     p += (size_t)DIM * DIM * 2;

    hipMemsetAsync(d_ws, 0, (size_t)(EBK + VBK) * sizeof(int), stream);

    dim3 blk(256);
    bin_kernel<<<NBIN, blk, 0, stream>>>(vertex, edges, ecur, vcur, erecs, vrecs);
    conv_w<<<1, blk, 0, stream>>>(W1, W2, W1T, W2T);
    agg_edges_srt<<<EBK, blk, 0, stream>>>(X, ecur, erecs, Xeb);
    agg_verts_mlp<<<VBK, blk, 0, stream>>>(Xeb, X0, vcur, vrecs, W1T, W2T, b1, b2, out);
}